// Round 6
// baseline (622.207 us; speedup 1.0000x reference)
//
#include <hip/hip_runtime.h>
#include <stdint.h>

#define HH 2048
#define BB 16384
#define NK (HH / 64)     // 32 K-steps of 64 bytes

typedef int v4i __attribute__((ext_vector_type(4)));

__device__ __forceinline__ int clip127(int v){
  v = v > 127 ? 127 : v;
  return v < -127 ? -127 : v;
}
// floor division by 720 (matches Python //)
__device__ __forceinline__ int fdiv720(int r){
  int q = r / 720;
  return q - ((r - q * 720) < 0 ? 1 : 0);
}

// Pack int32 (values in [-127,127]) -> int8. 16 elems / thread / iter.
__global__ void pack_i32_to_i8(const int* __restrict__ src, int8_t* __restrict__ dst, int n16){
  int stride = gridDim.x * blockDim.x;
  for (int i = blockIdx.x * blockDim.x + threadIdx.x; i < n16; i += stride){
    const int4* s = (const int4*)src + (size_t)i * 4;
    int4 a = s[0], b = s[1], c = s[2], d = s[3];
    int4 o;
    o.x = (a.x & 255) | ((a.y & 255) << 8) | ((a.z & 255) << 16) | (a.w << 24);
    o.y = (b.x & 255) | ((b.y & 255) << 8) | ((b.z & 255) << 16) | (b.w << 24);
    o.z = (c.x & 255) | ((c.y & 255) << 8) | ((c.z & 255) << 16) | (c.w << 24);
    o.w = (d.x & 255) | ((d.y & 255) << 8) | ((d.z & 255) << 16) | (d.w << 24);
    ((int4*)dst)[i] = o;
  }
}

// Duplicate first half of d_out into second half (int4). Fallback path only.
__global__ void dup_out(const int* __restrict__ src, int* __restrict__ dst, int n4){
  int stride = gridDim.x * blockDim.x;
  for (int i = blockIdx.x * blockDim.x + threadIdx.x; i < n4; i += stride)
    ((int4*)dst)[i] = ((const int4*)src)[i];
}

// Dual-GEMM 128x128 tile, double-buffered LDS (2x32KB), T3 minimal 2-phase
// schedule: STAGE(next) issued BEFORE compute(cur); ONE raw s_barrier +
// vmcnt(0) per K-step AFTER compute (loads overlap the ~650-cyc MFMA block).
// XCD-chunked block swizzle. acc1 = A1@B1^T, acc2 = A2@B2^T. i8 MFMA 16x16x64.
// PHASE 1: f_t = clip(clip(acc1//720)+clip(acc2//720)+bias); fg = f_t+127
//          fbuf[idx] = fg (int32); g8out[idx] = clip((fg*state)>>8)
// PHASE 2: h = clip(...); ns = clip(st + ((fbuf[idx]*(h-st))>>8));
//          fbuf[idx] = ns; if(out2) out2[idx] = ns
template<int PHASE>
__global__ __launch_bounds__(256, 2)
void gemm_dual(const int8_t* __restrict__ A1, const int8_t* __restrict__ A2,
               const int8_t* __restrict__ B1, const int8_t* __restrict__ B2,
               const int* __restrict__ bias,
               const int8_t* __restrict__ state8,
               int* fbuf, int8_t* __restrict__ g8out, int* __restrict__ out2)
{
  __shared__ __align__(16) int8_t lds[2 * 32768];   // dbuf x (A1,A2,B1,B2 x 8KB)
  const int tid  = threadIdx.x;
  const int lane = tid & 63;
  const int wave = tid >> 6;
  const int wrow = wave >> 1, wcol = wave & 1;

  // XCD-chunked bijective swizzle: 2048 blocks = 8 XCDs x 256-chunk.
  const int bid = blockIdx.x;
  const int wg  = (bid & 7) * 256 + (bid >> 3);
  const int rowbase = (wg >> 4) * 128;
  const int colbase = (wg & 15) * 128;

  v4i accA[4][4], accB[4][4];
  const v4i vzero = {0, 0, 0, 0};
#pragma unroll
  for (int m = 0; m < 4; m++)
#pragma unroll
    for (int n = 0; n < 4; n++){ accA[m][n] = vzero; accB[m][n] = vzero; }

  const int srow   = tid >> 2;   // 0..63 staging row within 64-row pass
  const int schunk = tid & 3;    // 16B chunk within 64B row
  const int chunk  = lane >> 4;  // frag-read 16B chunk
  const int rl     = lane & 15;

  // stage the 4 tiles' K-slice kk into buffer buf (linear LDS dest,
  // inverse-swizzled global source). 8 global_load_lds per thread.
  auto STAGE = [&](int buf, int kk){
    const int k0 = kk * 64;
    const int bb = buf * 32768;
#pragma unroll
    for (int p = 0; p < 2; p++){
      const int row = p * 64 + srow;
      const int swc = schunk ^ ((row >> 1) & 3);
      const size_t aoff = (size_t)(rowbase + row) * HH + k0 + swc * 16;
      const size_t boff = (size_t)(colbase + row) * HH + k0 + swc * 16;
      const int ldst = bb + p * 4096 + tid * 16;
      __builtin_amdgcn_global_load_lds((const __attribute__((address_space(1))) void*)(A1 + aoff),
                                       (__attribute__((address_space(3))) void*)(lds + ldst), 16, 0, 0);
      __builtin_amdgcn_global_load_lds((const __attribute__((address_space(1))) void*)(A2 + aoff),
                                       (__attribute__((address_space(3))) void*)(lds + 8192 + ldst), 16, 0, 0);
      __builtin_amdgcn_global_load_lds((const __attribute__((address_space(1))) void*)(B1 + boff),
                                       (__attribute__((address_space(3))) void*)(lds + 16384 + ldst), 16, 0, 0);
      __builtin_amdgcn_global_load_lds((const __attribute__((address_space(1))) void*)(B2 + boff),
                                       (__attribute__((address_space(3))) void*)(lds + 24576 + ldst), 16, 0, 0);
    }
  };

  // prologue: stage tile 0, drain, barrier
  STAGE(0, 0);
  asm volatile("s_waitcnt vmcnt(0)" ::: "memory");
  __builtin_amdgcn_s_barrier();

  int cur = 0;
  for (int kk = 0; kk < NK; ++kk){
    __builtin_amdgcn_sched_barrier(0);          // nothing hoists above the barrier
    if (kk + 1 < NK) STAGE(cur ^ 1, kk + 1);    // issue next-tile loads FIRST
    const int cb = cur * 32768;
    // pair 1: A1 x B1
    {
      v4i af[4], bf[4];
#pragma unroll
      for (int m = 0; m < 4; m++){
        const int row = wrow * 64 + m * 16 + rl;
        af[m] = *(const v4i*)(lds + cb + row * 64 + ((chunk ^ ((row >> 1) & 3)) << 4));
      }
#pragma unroll
      for (int n = 0; n < 4; n++){
        const int row = wcol * 64 + n * 16 + rl;
        bf[n] = *(const v4i*)(lds + cb + 16384 + row * 64 + ((chunk ^ ((row >> 1) & 3)) << 4));
      }
#pragma unroll
      for (int m = 0; m < 4; m++)
#pragma unroll
        for (int n = 0; n < 4; n++)
          accA[m][n] = __builtin_amdgcn_mfma_i32_16x16x64_i8(af[m], bf[n], accA[m][n], 0, 0, 0);
    }
    // pair 2: A2 x B2
    {
      v4i af[4], bf[4];
#pragma unroll
      for (int m = 0; m < 4; m++){
        const int row = wrow * 64 + m * 16 + rl;
        af[m] = *(const v4i*)(lds + cb + 8192 + row * 64 + ((chunk ^ ((row >> 1) & 3)) << 4));
      }
#pragma unroll
      for (int n = 0; n < 4; n++){
        const int row = wcol * 64 + n * 16 + rl;
        bf[n] = *(const v4i*)(lds + cb + 24576 + row * 64 + ((chunk ^ ((row >> 1) & 3)) << 4));
      }
#pragma unroll
      for (int m = 0; m < 4; m++)
#pragma unroll
        for (int n = 0; n < 4; n++)
          accB[m][n] = __builtin_amdgcn_mfma_i32_16x16x64_i8(af[m], bf[n], accB[m][n], 0, 0, 0);
    }
    __builtin_amdgcn_sched_barrier(0);          // compute pinned above the drain
    asm volatile("s_waitcnt vmcnt(0)" ::: "memory");  // next-tile loads landed
    __builtin_amdgcn_s_barrier();               // raw barrier: one per K-step
    cur ^= 1;
  }

  // epilogue: C/D layout col=lane&15, row=(lane>>4)*4+reg
  const int q = lane >> 4;
#pragma unroll
  for (int m = 0; m < 4; m++){
#pragma unroll
    for (int n = 0; n < 4; n++){
      const int gcol = colbase + wcol * 64 + n * 16 + rl;
      const int bval = bias[gcol];
#pragma unroll
      for (int r = 0; r < 4; r++){
        const int grow = rowbase + wrow * 64 + m * 16 + q * 4 + r;
        const size_t idx = (size_t)grow * HH + gcol;
        const int v1 = clip127(fdiv720(accA[m][n][r]));
        const int v2 = clip127(fdiv720(accB[m][n][r]));
        const int t  = clip127(v1 + v2 + bval);   // f_t or h_tilde
        const int st = state8[idx];
        if (PHASE == 1){
          const int fg = t + 127;
          fbuf[idx]  = fg;                          // int32, d_out first half
          g8out[idx] = (int8_t)clip127((fg * st) >> 8);
        } else {
          const int fg = fbuf[idx];
          const int ns = clip127(st + ((fg * (t - st)) >> 8));
          fbuf[idx] = ns;                           // output 0 (same-thread r/w)
          if (out2) out2[idx] = ns;                 // output 1 (ws path)
        }
      }
    }
  }
}

extern "C" void kernel_launch(void* const* d_in, const int* in_sizes, int n_in,
                              void* d_out, int out_size, void* d_ws, size_t ws_size,
                              hipStream_t stream){
  const int* x  = (const int*)d_in[0];
  const int* st = (const int*)d_in[1];
  const int* Wf = (const int*)d_in[2];
  const int* Uf = (const int*)d_in[3];
  const int* bf = (const int*)d_in[4];
  const int* Wh = (const int*)d_in[5];
  const int* Uh = (const int*)d_in[6];
  const int* bh = (const int*)d_in[7];

  const size_t NBH = (size_t)BB * HH;   // 33,554,432 elements
  const size_t NW  = (size_t)HH * HH;   //  4,194,304 elements
  const size_t need = 3 * NBH + 4 * NW; // 112 MiB of int8 scratch

  // d_out: int32 x 2*NBH (tuple). First half carries fg (int32) then new_state.
  // Scratch (x8|s8|g8|4 weights) goes to d_ws if large enough; else to d_out's
  // second half (then dup_out fills output 1 at the end).
  int*    out1   = (int*)d_out;
  const bool wsp = (ws_size >= need);
  int8_t* base   = wsp ? (int8_t*)d_ws : (int8_t*)d_out + NBH * 4;
  int8_t* x8  = base;
  int8_t* s8  = x8 + NBH;
  int8_t* g8  = s8 + NBH;
  int8_t* wf8 = g8 + NBH;
  int8_t* uf8 = wf8 + NW;
  int8_t* wh8 = uf8 + NW;
  int8_t* uh8 = wh8 + NW;

  pack_i32_to_i8<<<2048, 256, 0, stream>>>(x,  x8,  (int)(NBH / 16));
  pack_i32_to_i8<<<2048, 256, 0, stream>>>(st, s8,  (int)(NBH / 16));
  pack_i32_to_i8<<<1024, 256, 0, stream>>>(Wf, wf8, (int)(NW / 16));
  pack_i32_to_i8<<<1024, 256, 0, stream>>>(Uf, uf8, (int)(NW / 16));
  pack_i32_to_i8<<<1024, 256, 0, stream>>>(Wh, wh8, (int)(NW / 16));
  pack_i32_to_i8<<<1024, 256, 0, stream>>>(Uh, uh8, (int)(NW / 16));

  // grid: (16384/128) x (2048/128) = 2048 blocks of 256 threads
  gemm_dual<1><<<2048, 256, 0, stream>>>(x8, s8, wf8, uf8, bf, s8, out1, g8, nullptr);
  gemm_dual<2><<<2048, 256, 0, stream>>>(x8, g8, wh8, uh8, bh, s8, out1, nullptr,
                                         wsp ? out1 + NBH : nullptr);

  if (!wsp)
    dup_out<<<2048, 256, 0, stream>>>(out1, out1 + NBH, (int)(NBH / 4));
}

// Round 7
// 590.909 us; speedup vs baseline: 1.0530x; 1.0530x over previous
//
#include <hip/hip_runtime.h>
#include <stdint.h>

#define HH 2048
#define BB 16384
#define NK (HH / 64)     // 32 K-steps of 64 bytes

typedef int v4i __attribute__((ext_vector_type(4)));

__device__ __forceinline__ int clip127(int v){
  v = v > 127 ? 127 : v;
  return v < -127 ? -127 : v;
}
// floor division by 720 (matches Python //)
__device__ __forceinline__ int fdiv720(int r){
  int q = r / 720;
  return q - ((r - q * 720) < 0 ? 1 : 0);
}

// Pack int32 (values in [-127,127]) -> int8. 16 elems / thread / iter.
__global__ void pack_i32_to_i8(const int* __restrict__ src, int8_t* __restrict__ dst, int n16){
  int stride = gridDim.x * blockDim.x;
  for (int i = blockIdx.x * blockDim.x + threadIdx.x; i < n16; i += stride){
    const int4* s = (const int4*)src + (size_t)i * 4;
    int4 a = s[0], b = s[1], c = s[2], d = s[3];
    int4 o;
    o.x = (a.x & 255) | ((a.y & 255) << 8) | ((a.z & 255) << 16) | (a.w << 24);
    o.y = (b.x & 255) | ((b.y & 255) << 8) | ((b.z & 255) << 16) | (b.w << 24);
    o.z = (c.x & 255) | ((c.y & 255) << 8) | ((c.z & 255) << 16) | (c.w << 24);
    o.w = (d.x & 255) | ((d.y & 255) << 8) | ((d.z & 255) << 16) | (d.w << 24);
    ((int4*)dst)[i] = o;
  }
}

// Duplicate first half of d_out into second half (int4). Fallback path only.
__global__ void dup_out(const int* __restrict__ src, int* __restrict__ dst, int n4){
  int stride = gridDim.x * blockDim.x;
  for (int i = blockIdx.x * blockDim.x + threadIdx.x; i < n4; i += stride)
    ((int4*)dst)[i] = ((const int4*)src)[i];
}

// Dual-GEMM 128x128 tile, 8 waves (2 row x 4 col) of 64x32 per-wave sub-tiles
// -> acc only 64 regs/thread -> 4 waves/SIMD occupancy (vs 2 with 64x64).
// Serial R3-proven schedule: STAGE -> sync -> compute -> sync, single 32KB
// buffer. XCD-chunked block swizzle. acc1=A1@B1^T, acc2=A2@B2^T. i8 MFMA
// 16x16x64.
// PHASE 1: f_t = clip(clip(acc1//720)+clip(acc2//720)+bias); fg = f_t+127
//          fbuf[idx] = fg (int32); g8out[idx] = clip((fg*state)>>8)
// PHASE 2: h = clip(...); ns = clip(st + ((fbuf[idx]*(h-st))>>8));
//          fbuf[idx] = ns; if(out2) out2[idx] = ns
template<int PHASE>
__global__ __launch_bounds__(512, 4)
void gemm_dual(const int8_t* __restrict__ A1, const int8_t* __restrict__ A2,
               const int8_t* __restrict__ B1, const int8_t* __restrict__ B2,
               const int* __restrict__ bias,
               const int8_t* __restrict__ state8,
               int* fbuf, int8_t* __restrict__ g8out, int* __restrict__ out2)
{
  __shared__ __align__(16) int8_t lds[32768];   // A1,A2,B1,B2 x 8KB
  const int tid  = threadIdx.x;
  const int lane = tid & 63;
  const int wave = tid >> 6;        // 0..7
  const int wrow = wave >> 2;       // 0..1  -> rows wrow*64
  const int wcol = wave & 3;        // 0..3  -> cols wcol*32

  // XCD-chunked bijective swizzle: 2048 blocks = 8 XCDs x 256-chunk.
  const int bid = blockIdx.x;
  const int wg  = (bid & 7) * 256 + (bid >> 3);
  const int rowbase = (wg >> 4) * 128;
  const int colbase = (wg & 15) * 128;

  v4i accA[4][2], accB[4][2];
  const v4i vzero = {0, 0, 0, 0};
#pragma unroll
  for (int m = 0; m < 4; m++)
#pragma unroll
    for (int n = 0; n < 2; n++){ accA[m][n] = vzero; accB[m][n] = vzero; }

  const int srow   = tid >> 2;   // 0..127: all 128 rows in one pass
  const int schunk = tid & 3;    // 16B chunk within 64B row
  const int chunk  = lane >> 4;  // frag-read 16B chunk
  const int rl     = lane & 15;

  // per-thread staging addresses: base + kk*64 (4 global_load_lds / thread)
  const int  swc   = schunk ^ ((srow >> 1) & 3);      // inverse swizzle
  const size_t aoff0 = (size_t)(rowbase + srow) * HH + swc * 16;
  const size_t boff0 = (size_t)(colbase + srow) * HH + swc * 16;
  const int  ldst  = tid * 16;

  for (int kk = 0; kk < NK; ++kk){
    const int k0 = kk * 64;
    __builtin_amdgcn_global_load_lds((const __attribute__((address_space(1))) void*)(A1 + aoff0 + k0),
                                     (__attribute__((address_space(3))) void*)(lds + ldst), 16, 0, 0);
    __builtin_amdgcn_global_load_lds((const __attribute__((address_space(1))) void*)(A2 + aoff0 + k0),
                                     (__attribute__((address_space(3))) void*)(lds + 8192 + ldst), 16, 0, 0);
    __builtin_amdgcn_global_load_lds((const __attribute__((address_space(1))) void*)(B1 + boff0 + k0),
                                     (__attribute__((address_space(3))) void*)(lds + 16384 + ldst), 16, 0, 0);
    __builtin_amdgcn_global_load_lds((const __attribute__((address_space(1))) void*)(B2 + boff0 + k0),
                                     (__attribute__((address_space(3))) void*)(lds + 24576 + ldst), 16, 0, 0);
    __syncthreads();   // drain staging, all waves see the tile

    // pair 1: A1 x B1
    {
      v4i af[4], bf[2];
#pragma unroll
      for (int m = 0; m < 4; m++){
        const int row = wrow * 64 + m * 16 + rl;
        af[m] = *(const v4i*)(lds + row * 64 + ((chunk ^ ((row >> 1) & 3)) << 4));
      }
#pragma unroll
      for (int n = 0; n < 2; n++){
        const int row = wcol * 32 + n * 16 + rl;
        bf[n] = *(const v4i*)(lds + 16384 + row * 64 + ((chunk ^ ((row >> 1) & 3)) << 4));
      }
#pragma unroll
      for (int m = 0; m < 4; m++)
#pragma unroll
        for (int n = 0; n < 2; n++)
          accA[m][n] = __builtin_amdgcn_mfma_i32_16x16x64_i8(af[m], bf[n], accA[m][n], 0, 0, 0);
    }
    // pair 2: A2 x B2
    {
      v4i af[4], bf[2];
#pragma unroll
      for (int m = 0; m < 4; m++){
        const int row = wrow * 64 + m * 16 + rl;
        af[m] = *(const v4i*)(lds + 8192 + row * 64 + ((chunk ^ ((row >> 1) & 3)) << 4));
      }
#pragma unroll
      for (int n = 0; n < 2; n++){
        const int row = wcol * 32 + n * 16 + rl;
        bf[n] = *(const v4i*)(lds + 24576 + row * 64 + ((chunk ^ ((row >> 1) & 3)) << 4));
      }
#pragma unroll
      for (int m = 0; m < 4; m++)
#pragma unroll
        for (int n = 0; n < 2; n++)
          accB[m][n] = __builtin_amdgcn_mfma_i32_16x16x64_i8(af[m], bf[n], accB[m][n], 0, 0, 0);
    }
    __syncthreads();   // all reads done before next stage overwrites
  }

  // epilogue: C/D layout col=lane&15, row=(lane>>4)*4+reg
  const int q = lane >> 4;
#pragma unroll
  for (int m = 0; m < 4; m++){
#pragma unroll
    for (int n = 0; n < 2; n++){
      const int gcol = colbase + wcol * 32 + n * 16 + rl;
      const int bval = bias[gcol];
#pragma unroll
      for (int r = 0; r < 4; r++){
        const int grow = rowbase + wrow * 64 + m * 16 + q * 4 + r;
        const size_t idx = (size_t)grow * HH + gcol;
        const int v1 = clip127(fdiv720(accA[m][n][r]));
        const int v2 = clip127(fdiv720(accB[m][n][r]));
        const int t  = clip127(v1 + v2 + bval);   // f_t or h_tilde
        const int st = state8[idx];
        if (PHASE == 1){
          const int fg = t + 127;
          fbuf[idx]  = fg;                          // int32, d_out first half
          g8out[idx] = (int8_t)clip127((fg * st) >> 8);
        } else {
          const int fg = fbuf[idx];
          const int ns = clip127(st + ((fg * (t - st)) >> 8));
          fbuf[idx] = ns;                           // output 0 (same-thread r/w)
          if (out2) out2[idx] = ns;                 // output 1 (ws path)
        }
      }
    }
  }
}

extern "C" void kernel_launch(void* const* d_in, const int* in_sizes, int n_in,
                              void* d_out, int out_size, void* d_ws, size_t ws_size,
                              hipStream_t stream){
  const int* x  = (const int*)d_in[0];
  const int* st = (const int*)d_in[1];
  const int* Wf = (const int*)d_in[2];
  const int* Uf = (const int*)d_in[3];
  const int* bf = (const int*)d_in[4];
  const int* Wh = (const int*)d_in[5];
  const int* Uh = (const int*)d_in[6];
  const int* bh = (const int*)d_in[7];

  const size_t NBH = (size_t)BB * HH;   // 33,554,432 elements
  const size_t NW  = (size_t)HH * HH;   //  4,194,304 elements
  const size_t need = 3 * NBH + 4 * NW; // 112 MiB of int8 scratch

  // d_out: int32 x 2*NBH (tuple). First half carries fg (int32) then new_state.
  // Scratch (x8|s8|g8|4 weights) goes to d_ws if large enough; else to d_out's
  // second half (then dup_out fills output 1 at the end).
  int*    out1   = (int*)d_out;
  const bool wsp = (ws_size >= need);
  int8_t* base   = wsp ? (int8_t*)d_ws : (int8_t*)d_out + NBH * 4;
  int8_t* x8  = base;
  int8_t* s8  = x8 + NBH;
  int8_t* g8  = s8 + NBH;
  int8_t* wf8 = g8 + NBH;
  int8_t* uf8 = wf8 + NW;
  int8_t* wh8 = uf8 + NW;
  int8_t* uh8 = wh8 + NW;

  pack_i32_to_i8<<<2048, 256, 0, stream>>>(x,  x8,  (int)(NBH / 16));
  pack_i32_to_i8<<<2048, 256, 0, stream>>>(st, s8,  (int)(NBH / 16));
  pack_i32_to_i8<<<1024, 256, 0, stream>>>(Wf, wf8, (int)(NW / 16));
  pack_i32_to_i8<<<1024, 256, 0, stream>>>(Uf, uf8, (int)(NW / 16));
  pack_i32_to_i8<<<1024, 256, 0, stream>>>(Wh, wh8, (int)(NW / 16));
  pack_i32_to_i8<<<1024, 256, 0, stream>>>(Uh, uh8, (int)(NW / 16));

  // grid: (16384/128) x (2048/128) = 2048 blocks of 512 threads
  gemm_dual<1><<<2048, 512, 0, stream>>>(x8, s8, wf8, uf8, bf, s8, out1, g8, nullptr);
  gemm_dual<2><<<2048, 512, 0, stream>>>(x8, g8, wh8, uh8, bh, s8, out1, nullptr,
                                         wsp ? out1 + NBH : nullptr);

  if (!wsp)
    dup_out<<<2048, 256, 0, stream>>>(out1, out1 + NBH, (int)(NBH / 4));
}